// Round 1
// baseline (476.161 us; speedup 1.0000x reference)
//
#include <hip/hip_runtime.h>
#include <hip/hip_bf16.h>

typedef __attribute__((ext_vector_type(8))) short short8;
typedef __attribute__((ext_vector_type(4))) short short4v;
typedef __attribute__((ext_vector_type(4))) float float4v;

#define LDS_BYTES 144384
// LDS arena (bytes):
//  Xbf : [64][264] bf16 @ 0      (33792) — live whole kernel (residual)
//  Vt  : 8 x [32][72] bf16 @ 33792 (36864) — per-head V^T
//  Q   : [64][264] bf16 @ 70656  (33792)
//  K   : [64][264] bf16 @ 104448 (33792)
//  P   : 8 x [64][72] bf16 @ 70656 (73728)  — aliases Q+K after S done
//  CTX : [64][264] bf16 @ 33792  (33792)    — aliases Vt after PV done
//  Y   : [64][256] f32  @ 70656  (65536)    — aliases P after PV done
#define XBF_OFF   0
#define VT_OFF    33792
#define Q_OFF     70656
#define K_OFF     104448
#define P_OFF     70656
#define CTX_OFF   33792
#define Y_OFF     70656

__device__ __forceinline__ unsigned short f2bf(float f) {
    union { float f; unsigned int u; } v; v.f = f;
    unsigned int r = v.u + 0x7FFFu + ((v.u >> 16) & 1u);
    return (unsigned short)(r >> 16);
}
__device__ __forceinline__ float bf2f(unsigned short h) {
    union { unsigned int u; float f; } v; v.u = ((unsigned int)h) << 16;
    return v.f;
}

// Pre-convert weights fp32 -> bf16 in MFMA B-fragment order:
// elem index = ((ks*16 + nt2)*64 + lane)*8 + j ; c = ks*32 + (lane>>4)*8 + j ;
// o = nt2*16 + (lane&15) ; value = W[c*256 + o].
// Matrices: 0=wq 1=wk 2=wv (layout [C][H*KD]) 3=wo (layout [H*KD][C]) — same formula.
__global__ void prep_weights(const float* __restrict__ wq, const float* __restrict__ wk,
                             const float* __restrict__ wv, const float* __restrict__ wo,
                             unsigned short* __restrict__ wfrag) {
    int tid = blockIdx.x * 256 + threadIdx.x;
    if (tid >= 4 * 65536) return;
    int m = tid >> 16;
    int e = tid & 65535;
    int j = e & 7;
    int lane = (e >> 3) & 63;
    int nt2 = (e >> 9) & 15;
    int ks = e >> 13;
    int c = ks * 32 + (lane >> 4) * 8 + j;
    int o = nt2 * 16 + (lane & 15);
    const float* W = (m == 0) ? wq : (m == 1) ? wk : (m == 2) ? wv : wo;
    wfrag[tid] = f2bf(W[c * 256 + o]);
}

__global__ __launch_bounds__(512) void swin_fused(
    const float* __restrict__ x,
    const unsigned short* __restrict__ wfrag,
    const float* __restrict__ bq, const float* __restrict__ bk,
    const float* __restrict__ bv, const float* __restrict__ bo,
    const float* __restrict__ gamma, const float* __restrict__ beta,
    float* __restrict__ out)
{
    extern __shared__ char smem[];
    const int tid = threadIdx.x;
    const int w   = tid >> 6;   // wave id = head id
    const int l   = tid & 63;
    const int l15 = l & 15;
    const int l4  = l >> 4;

    const int blk = blockIdx.x;
    const int bb  = blk >> 8;
    const int wh  = (blk >> 4) & 15;
    const int ww  = blk & 15;

    unsigned short* Xbf = (unsigned short*)(smem + XBF_OFF);

    // ---- Phase 0: stage X (fp32 -> bf16), shifted-window gather, rows 49..63 zero ----
    for (int idx = tid; idx < 64 * 64; idx += 512) {
        const int tok = idx >> 6;
        const int c4  = idx & 63;
        float4v f = (float4v){0.f, 0.f, 0.f, 0.f};
        if (tok < 49) {
            const int i = tok / 7;
            const int j = tok - 7 * i;
            int gr = wh * 7 + i + 3; if (gr >= 112) gr -= 112;
            int gc = ww * 7 + j + 3; if (gc >= 112) gc -= 112;
            f = *(const float4v*)(x + (((size_t)bb * 112 + gr) * 112 + gc) * 256 + c4 * 4);
        }
        short4v h;
        h.x = (short)f2bf(f.x); h.y = (short)f2bf(f.y);
        h.z = (short)f2bf(f.z); h.w = (short)f2bf(f.w);
        *(short4v*)((char*)Xbf + tok * 528 + c4 * 8) = h;
    }
    __syncthreads();

    unsigned short* Qs = (unsigned short*)(smem + Q_OFF);
    unsigned short* Ks = (unsigned short*)(smem + K_OFF);
    unsigned short* Vt = (unsigned short*)(smem + VT_OFF);

    // ---- Phase 1: QKV projection. Wave w computes output cols [32w, 32w+32) of each ----
    const float* biases[3] = { bq, bk, bv };
#pragma unroll
    for (int m = 0; m < 3; ++m) {
        float4v acc[4][2];
#pragma unroll
        for (int mt = 0; mt < 4; ++mt)
#pragma unroll
            for (int nt = 0; nt < 2; ++nt)
                acc[mt][nt] = (float4v){0.f, 0.f, 0.f, 0.f};
        const unsigned short* wmat = wfrag + m * 65536;
#pragma unroll
        for (int ks = 0; ks < 8; ++ks) {
            short8 afr[4];
#pragma unroll
            for (int mt = 0; mt < 4; ++mt)
                afr[mt] = *(const short8*)((const char*)Xbf + (mt * 16 + l15) * 528 + (ks * 32 + l4 * 8) * 2);
#pragma unroll
            for (int nt = 0; nt < 2; ++nt) {
                const int nt2 = 2 * w + nt;
                short8 bfr = *(const short8*)(wmat + ((ks * 16 + nt2) * 64 + l) * 8);
#pragma unroll
                for (int mt = 0; mt < 4; ++mt)
                    acc[mt][nt] = __builtin_amdgcn_mfma_f32_16x16x32_bf16(afr[mt], bfr, acc[mt][nt], 0, 0, 0);
            }
        }
        // bias add + store (Q,K packed [64][264]; V transposed per head [32][72])
#pragma unroll
        for (int nt = 0; nt < 2; ++nt) {
            const int o = 32 * w + nt * 16 + l15;
            const float bias = biases[m][o];
#pragma unroll
            for (int mt = 0; mt < 4; ++mt)
#pragma unroll
                for (int r = 0; r < 4; ++r) {
                    const float v = acc[mt][nt][r] + bias;
                    const int tok = mt * 16 + l4 * 4 + r;
                    const unsigned short hv = f2bf(v);
                    if (m == 0) {
                        *(unsigned short*)((char*)Qs + tok * 528 + o * 2) = hv;
                    } else if (m == 1) {
                        *(unsigned short*)((char*)Ks + tok * 528 + o * 2) = hv;
                    } else {
                        const int d = nt * 16 + l15;
                        *(unsigned short*)((char*)Vt + w * 4608 + d * 144 + tok * 2) = hv;
                    }
                }
        }
    }
    // No barrier: wave w's S reads only cols [32w,32w+32) of Q/K and head w of Vt — self-written.

    // ---- Phase 2: S = Q Kt for head w ----
    float4v sa[4][4];
#pragma unroll
    for (int mt = 0; mt < 4; ++mt)
#pragma unroll
        for (int nt = 0; nt < 4; ++nt)
            sa[mt][nt] = (float4v){0.f, 0.f, 0.f, 0.f};
    {
        short8 afr[4], bfr[4];
#pragma unroll
        for (int mt = 0; mt < 4; ++mt)
            afr[mt] = *(const short8*)((const char*)Qs + (mt * 16 + l15) * 528 + (32 * w + l4 * 8) * 2);
#pragma unroll
        for (int nt = 0; nt < 4; ++nt)
            bfr[nt] = *(const short8*)((const char*)Ks + (nt * 16 + l15) * 528 + (32 * w + l4 * 8) * 2);
#pragma unroll
        for (int mt = 0; mt < 4; ++mt)
#pragma unroll
            for (int nt = 0; nt < 4; ++nt)
                sa[mt][nt] = __builtin_amdgcn_mfma_f32_16x16x32_bf16(afr[mt], bfr[nt], sa[mt][nt], 0, 0, 0);
    }
    __syncthreads();   // all waves done reading Q/K before P overwrites them

    // ---- Phase 3: softmax (wave-parallel, 16-lane groups) + write P bf16 ----
    unsigned short* Pw = (unsigned short*)(smem + P_OFF + w * 9216);
    const float SCALE = 0.17677669529663687f;  // 1/sqrt(32)
#pragma unroll
    for (int mt = 0; mt < 4; ++mt) {
#pragma unroll
        for (int r = 0; r < 4; ++r) {
            float s[4];
#pragma unroll
            for (int nt = 0; nt < 4; ++nt) {
                s[nt] = sa[mt][nt][r] * SCALE;
                if (nt * 16 + l15 >= 49) s[nt] = -1e30f;
            }
            float mx = fmaxf(fmaxf(s[0], s[1]), fmaxf(s[2], s[3]));
#pragma unroll
            for (int msk = 1; msk < 16; msk <<= 1) mx = fmaxf(mx, __shfl_xor(mx, msk, 64));
            float p[4], sum = 0.f;
#pragma unroll
            for (int nt = 0; nt < 4; ++nt) { p[nt] = __expf(s[nt] - mx); sum += p[nt]; }
#pragma unroll
            for (int msk = 1; msk < 16; msk <<= 1) sum += __shfl_xor(sum, msk, 64);
            const float inv = 1.f / sum;
            const int tok = mt * 16 + l4 * 4 + r;
#pragma unroll
            for (int nt = 0; nt < 4; ++nt)
                *(unsigned short*)((char*)Pw + tok * 144 + (nt * 16 + l15) * 2) = f2bf(p[nt] * inv);
        }
    }
    // No barrier: PV reads only this wave's P and this wave's Vt.

    // ---- Phase 4: ctx = P V for head w ----
    float4v ca[4][2];
#pragma unroll
    for (int mt = 0; mt < 4; ++mt)
#pragma unroll
        for (int nt = 0; nt < 2; ++nt)
            ca[mt][nt] = (float4v){0.f, 0.f, 0.f, 0.f};
#pragma unroll
    for (int ks = 0; ks < 2; ++ks) {
        short8 afr[4];
#pragma unroll
        for (int mt = 0; mt < 4; ++mt)
            afr[mt] = *(const short8*)((const char*)Pw + (mt * 16 + l15) * 144 + (ks * 32 + l4 * 8) * 2);
#pragma unroll
        for (int nt = 0; nt < 2; ++nt) {
            short8 bfr = *(const short8*)((const char*)Vt + w * 4608 + (nt * 16 + l15) * 144 + (ks * 32 + l4 * 8) * 2);
#pragma unroll
            for (int mt = 0; mt < 4; ++mt)
                ca[mt][nt] = __builtin_amdgcn_mfma_f32_16x16x32_bf16(afr[mt], bfr, ca[mt][nt], 0, 0, 0);
        }
    }
    __syncthreads();   // all PV reads of Vt done before CTX overwrites it

    // ---- write ctx bf16 packed [64][264] ----
    unsigned short* Ctx = (unsigned short*)(smem + CTX_OFF);
#pragma unroll
    for (int nt = 0; nt < 2; ++nt) {
        const int o = 32 * w + nt * 16 + l15;
#pragma unroll
        for (int mt = 0; mt < 4; ++mt)
#pragma unroll
            for (int r = 0; r < 4; ++r) {
                const int tok = mt * 16 + l4 * 4 + r;
                *(unsigned short*)((char*)Ctx + tok * 528 + o * 2) = f2bf(ca[mt][nt][r]);
            }
    }
    __syncthreads();

    // ---- Phase 5: out-proj: attn = ctx @ wo ; wave w -> cout [32w, 32w+32) ----
    float4v oa[4][2];
#pragma unroll
    for (int mt = 0; mt < 4; ++mt)
#pragma unroll
        for (int nt = 0; nt < 2; ++nt)
            oa[mt][nt] = (float4v){0.f, 0.f, 0.f, 0.f};
    const unsigned short* womat = wfrag + 3 * 65536;
#pragma unroll
    for (int ks = 0; ks < 8; ++ks) {
        short8 afr[4];
#pragma unroll
        for (int mt = 0; mt < 4; ++mt)
            afr[mt] = *(const short8*)((const char*)Ctx + (mt * 16 + l15) * 528 + (ks * 32 + l4 * 8) * 2);
#pragma unroll
        for (int nt = 0; nt < 2; ++nt) {
            short8 bfr = *(const short8*)(womat + ((ks * 16 + 2 * w + nt) * 64 + l) * 8);
#pragma unroll
            for (int mt = 0; mt < 4; ++mt)
                oa[mt][nt] = __builtin_amdgcn_mfma_f32_16x16x32_bf16(afr[mt], bfr, oa[mt][nt], 0, 0, 0);
        }
    }
    // y = attn + bo + x(residual from bf16) -> Y fp32 [64][256] (aliases dead P region)
    float* Y = (float*)(smem + Y_OFF);
#pragma unroll
    for (int nt = 0; nt < 2; ++nt) {
        const int cout = 32 * w + nt * 16 + l15;
        const float bias = bo[cout];
#pragma unroll
        for (int mt = 0; mt < 4; ++mt)
#pragma unroll
            for (int r = 0; r < 4; ++r) {
                const int tok = mt * 16 + l4 * 4 + r;
                const float xv = bf2f(Xbf[tok * 264 + cout]);
                Y[tok * 256 + cout] = oa[mt][nt][r] + bias + xv;
            }
    }
    __syncthreads();

    // ---- Phase 6: LayerNorm per token (one token per wave) + rolled scatter store ----
    const float4v g4  = *(const float4v*)(gamma + l * 4);
    const float4v be4 = *(const float4v*)(beta + l * 4);
#pragma unroll
    for (int t = 0; t < 7; ++t) {
        const int tok = w + t * 8;
        if (tok < 49) {
            float4v f = *(const float4v*)(Y + tok * 256 + l * 4);
            float sum = f.x + f.y + f.z + f.w;
            float sq  = f.x * f.x + f.y * f.y + f.z * f.z + f.w * f.w;
#pragma unroll
            for (int msk = 1; msk < 64; msk <<= 1) {
                sum += __shfl_xor(sum, msk, 64);
                sq  += __shfl_xor(sq,  msk, 64);
            }
            const float mu   = sum * (1.f / 256.f);
            const float var  = sq * (1.f / 256.f) - mu * mu;
            const float rstd = rsqrtf(var + 1e-3f);
            const int i = tok / 7;
            const int j = tok - 7 * i;
            int gr = wh * 7 + i + 3; if (gr >= 112) gr -= 112;
            int gc = ww * 7 + j + 3; if (gc >= 112) gc -= 112;
            float4v o4;
            o4.x = (f.x - mu) * rstd * g4.x + be4.x;
            o4.y = (f.y - mu) * rstd * g4.y + be4.y;
            o4.z = (f.z - mu) * rstd * g4.z + be4.z;
            o4.w = (f.w - mu) * rstd * g4.w + be4.w;
            *(float4v*)(out + (((size_t)bb * 112 + gr) * 112 + gc) * 256 + l * 4) = o4;
        }
    }
}

extern "C" void kernel_launch(void* const* d_in, const int* in_sizes, int n_in,
                              void* d_out, int out_size, void* d_ws, size_t ws_size,
                              hipStream_t stream) {
    const float* x     = (const float*)d_in[0];
    const float* wq    = (const float*)d_in[1];
    const float* bq    = (const float*)d_in[2];
    const float* wk    = (const float*)d_in[3];
    const float* bk    = (const float*)d_in[4];
    const float* wv    = (const float*)d_in[5];
    const float* bv    = (const float*)d_in[6];
    const float* wo    = (const float*)d_in[7];
    const float* bo    = (const float*)d_in[8];
    const float* gamma = (const float*)d_in[9];
    const float* beta  = (const float*)d_in[10];
    float* out = (float*)d_out;
    unsigned short* wfrag = (unsigned short*)d_ws;   // 4 * 65536 bf16 = 512 KB

    prep_weights<<<1024, 256, 0, stream>>>(wq, wk, wv, wo, wfrag);

    hipFuncSetAttribute((const void*)swin_fused,
                        hipFuncAttributeMaxDynamicSharedMemorySize, LDS_BYTES);
    swin_fused<<<4096, 512, LDS_BYTES, stream>>>(x, wfrag, bq, bk, bv, bo, gamma, beta, out);
}

// Round 2
// 333.756 us; speedup vs baseline: 1.4267x; 1.4267x over previous
//
#include <hip/hip_runtime.h>
#include <hip/hip_bf16.h>

typedef __attribute__((ext_vector_type(8))) short short8;
typedef __attribute__((ext_vector_type(4))) short short4v;
typedef __attribute__((ext_vector_type(4))) float float4v;

#define LDS_BYTES 144384
// LDS arena (bytes):
//  Xbf : [64][264] bf16 @ 0      (33792) — live whole kernel (residual)
//  Vt  : 8 x [32][72] bf16 @ 33792 (36864) — per-head V^T
//  Q   : [64][264] bf16 @ 70656  (33792)
//  K   : [64][264] bf16 @ 104448 (33792)
//  P   : 8 x [64][72] bf16 @ 70656 (73728)  — aliases Q+K after S done
//  CTX : [64][264] bf16 @ 33792  (33792)    — aliases Vt after PV done
//  Y   : [64][260] f32  @ 70656  (66560)    — aliases P after PV done
#define XBF_OFF   0
#define VT_OFF    33792
#define Q_OFF     70656
#define K_OFF     104448
#define P_OFF     70656
#define CTX_OFF   33792
#define Y_OFF     70656

__device__ __forceinline__ unsigned short f2bf(float f) {
    union { float f; unsigned int u; } v; v.f = f;
    unsigned int r = v.u + 0x7FFFu + ((v.u >> 16) & 1u);
    return (unsigned short)(r >> 16);
}
__device__ __forceinline__ float bf2f(unsigned short h) {
    union { unsigned int u; float f; } v; v.u = ((unsigned int)h) << 16;
    return v.f;
}

// Pre-convert weights fp32 -> bf16 in MFMA B-fragment order:
// elem index = ((ks*16 + nt2)*64 + lane)*8 + j ; c = ks*32 + (lane>>4)*8 + j ;
// o = nt2*16 + (lane&15) ; value = W[c*256 + o].
__global__ void prep_weights(const float* __restrict__ wq, const float* __restrict__ wk,
                             const float* __restrict__ wv, const float* __restrict__ wo,
                             unsigned short* __restrict__ wfrag) {
    int tid = blockIdx.x * 256 + threadIdx.x;
    if (tid >= 4 * 65536) return;
    int m = tid >> 16;
    int e = tid & 65535;
    int j = e & 7;
    int lane = (e >> 3) & 63;
    int nt2 = (e >> 9) & 15;
    int ks = e >> 13;
    int c = ks * 32 + (lane >> 4) * 8 + j;
    int o = nt2 * 16 + (lane & 15);
    const float* W = (m == 0) ? wq : (m == 1) ? wk : (m == 2) ? wv : wo;
    wfrag[tid] = f2bf(W[c * 256 + o]);
}

__global__ __launch_bounds__(1024, 4) void swin_fused(
    const float* __restrict__ x,
    const unsigned short* __restrict__ wfrag,
    const float* __restrict__ bq, const float* __restrict__ bk,
    const float* __restrict__ bv, const float* __restrict__ bo,
    const float* __restrict__ gamma, const float* __restrict__ beta,
    float* __restrict__ out)
{
    extern __shared__ char smem[];
    const int tid = threadIdx.x;
    const int w    = tid >> 6;    // wave id 0..15
    const int h    = w & 7;       // head
    const int half = w >> 3;      // token-half / nt-half
    const int l   = tid & 63;
    const int l15 = l & 15;
    const int l4  = l >> 4;
    const int nt2 = 2 * h + half; // 16-col output group owned by this wave

    const int blk = blockIdx.x;
    const int bb  = blk >> 8;
    const int wh  = (blk >> 4) & 15;
    const int ww  = blk & 15;

    unsigned short* Xbf = (unsigned short*)(smem + XBF_OFF);

    // ---- Phase 0: stage X (fp32 -> bf16), shifted-window gather, rows 49..63 zero ----
    for (int idx = tid; idx < 64 * 64; idx += 1024) {
        const int tok = idx >> 6;
        const int c4  = idx & 63;
        float4v f = (float4v){0.f, 0.f, 0.f, 0.f};
        if (tok < 49) {
            const int i = tok / 7;
            const int j = tok - 7 * i;
            int gr = wh * 7 + i + 3; if (gr >= 112) gr -= 112;
            int gc = ww * 7 + j + 3; if (gc >= 112) gc -= 112;
            f = *(const float4v*)(x + (((size_t)bb * 112 + gr) * 112 + gc) * 256 + c4 * 4);
        }
        short4v hv;
        hv.x = (short)f2bf(f.x); hv.y = (short)f2bf(f.y);
        hv.z = (short)f2bf(f.z); hv.w = (short)f2bf(f.w);
        *(short4v*)((char*)Xbf + tok * 528 + c4 * 8) = hv;
    }
    __syncthreads();

    unsigned short* Qs = (unsigned short*)(smem + Q_OFF);
    unsigned short* Ks = (unsigned short*)(smem + K_OFF);
    unsigned short* Vt = (unsigned short*)(smem + VT_OFF);

    // ---- Phase 1: QKV projection. Wave (h,half) -> output cols [16*nt2, +16) of each ----
    const float* biases[3] = { bq, bk, bv };
#pragma unroll
    for (int m = 0; m < 3; ++m) {
        float4v acc[4];
#pragma unroll
        for (int mt = 0; mt < 4; ++mt) acc[mt] = (float4v){0.f, 0.f, 0.f, 0.f};
        const unsigned short* wmat = wfrag + m * 65536;
#pragma unroll
        for (int ks = 0; ks < 8; ++ks) {
            short8 bfr = *(const short8*)(wmat + ((ks * 16 + nt2) * 64 + l) * 8);
#pragma unroll
            for (int mt = 0; mt < 4; ++mt) {
                short8 afr = *(const short8*)((const char*)Xbf + (mt * 16 + l15) * 528 + (ks * 32 + l4 * 8) * 2);
                acc[mt] = __builtin_amdgcn_mfma_f32_16x16x32_bf16(afr, bfr, acc[mt], 0, 0, 0);
            }
        }
        const int o = nt2 * 16 + l15;
        const float bias = biases[m][o];
#pragma unroll
        for (int mt = 0; mt < 4; ++mt)
#pragma unroll
            for (int r = 0; r < 4; ++r) {
                const float v = acc[mt][r] + bias;
                const int tok = mt * 16 + l4 * 4 + r;
                const unsigned short hv = f2bf(v);
                if (m == 0) {
                    *(unsigned short*)((char*)Qs + tok * 528 + o * 2) = hv;
                } else if (m == 1) {
                    *(unsigned short*)((char*)Ks + tok * 528 + o * 2) = hv;
                } else {
                    const int d = half * 16 + l15;
                    *(unsigned short*)((char*)Vt + h * 4608 + d * 144 + tok * 2) = hv;
                }
            }
    }
    __syncthreads();   // cross-wave: S needs both halves' Q/K cols

    // ---- Phase 2: S rows [32*half, +32) for head h ----
    float4v sa[2][4];
#pragma unroll
    for (int mtl = 0; mtl < 2; ++mtl)
#pragma unroll
        for (int nt = 0; nt < 4; ++nt)
            sa[mtl][nt] = (float4v){0.f, 0.f, 0.f, 0.f};
    {
        short8 afr[2], bfr[4];
#pragma unroll
        for (int mtl = 0; mtl < 2; ++mtl)
            afr[mtl] = *(const short8*)((const char*)Qs + ((2 * half + mtl) * 16 + l15) * 528 + (32 * h + l4 * 8) * 2);
#pragma unroll
        for (int nt = 0; nt < 4; ++nt)
            bfr[nt] = *(const short8*)((const char*)Ks + (nt * 16 + l15) * 528 + (32 * h + l4 * 8) * 2);
#pragma unroll
        for (int mtl = 0; mtl < 2; ++mtl)
#pragma unroll
            for (int nt = 0; nt < 4; ++nt)
                sa[mtl][nt] = __builtin_amdgcn_mfma_f32_16x16x32_bf16(afr[mtl], bfr[nt], sa[mtl][nt], 0, 0, 0);
    }
    __syncthreads();   // all waves done reading Q/K before P overwrites them

    // ---- Phase 3: softmax (16-lane groups) + write P bf16 ----
    unsigned short* Pw = (unsigned short*)(smem + P_OFF + h * 9216);
    const float SCALE = 0.17677669529663687f;  // 1/sqrt(32)
#pragma unroll
    for (int mtl = 0; mtl < 2; ++mtl) {
#pragma unroll
        for (int r = 0; r < 4; ++r) {
            float s[4];
#pragma unroll
            for (int nt = 0; nt < 4; ++nt) {
                s[nt] = sa[mtl][nt][r] * SCALE;
                if (nt * 16 + l15 >= 49) s[nt] = -1e30f;
            }
            float mx = fmaxf(fmaxf(s[0], s[1]), fmaxf(s[2], s[3]));
#pragma unroll
            for (int msk = 1; msk < 16; msk <<= 1) mx = fmaxf(mx, __shfl_xor(mx, msk, 64));
            float p[4], sum = 0.f;
#pragma unroll
            for (int nt = 0; nt < 4; ++nt) { p[nt] = __expf(s[nt] - mx); sum += p[nt]; }
#pragma unroll
            for (int msk = 1; msk < 16; msk <<= 1) sum += __shfl_xor(sum, msk, 64);
            const float inv = 1.f / sum;
            const int tok = (2 * half + mtl) * 16 + l4 * 4 + r;
#pragma unroll
            for (int nt = 0; nt < 4; ++nt)
                *(unsigned short*)((char*)Pw + tok * 144 + (nt * 16 + l15) * 2) = f2bf(p[nt] * inv);
        }
    }
    // No barrier: PV reads only this wave's P rows and head-h Vt (covered by proj barrier).

    // ---- Phase 4: ctx rows [32*half,+32) = P V for head h ----
    float4v ca[2][2];
#pragma unroll
    for (int mtl = 0; mtl < 2; ++mtl)
#pragma unroll
        for (int nt = 0; nt < 2; ++nt)
            ca[mtl][nt] = (float4v){0.f, 0.f, 0.f, 0.f};
#pragma unroll
    for (int ks = 0; ks < 2; ++ks) {
        short8 afr[2];
#pragma unroll
        for (int mtl = 0; mtl < 2; ++mtl)
            afr[mtl] = *(const short8*)((const char*)Pw + ((2 * half + mtl) * 16 + l15) * 144 + (ks * 32 + l4 * 8) * 2);
#pragma unroll
        for (int nt = 0; nt < 2; ++nt) {
            short8 bfr = *(const short8*)((const char*)Vt + h * 4608 + (nt * 16 + l15) * 144 + (ks * 32 + l4 * 8) * 2);
#pragma unroll
            for (int mtl = 0; mtl < 2; ++mtl)
                ca[mtl][nt] = __builtin_amdgcn_mfma_f32_16x16x32_bf16(afr[mtl], bfr, ca[mtl][nt], 0, 0, 0);
        }
    }
    __syncthreads();   // all PV reads of Vt done before CTX overwrites it

    // ---- write ctx bf16 packed [64][264] ----
    unsigned short* Ctx = (unsigned short*)(smem + CTX_OFF);
#pragma unroll
    for (int nt = 0; nt < 2; ++nt) {
        const int o = 32 * h + nt * 16 + l15;
#pragma unroll
        for (int mtl = 0; mtl < 2; ++mtl)
#pragma unroll
            for (int r = 0; r < 4; ++r) {
                const int tok = (2 * half + mtl) * 16 + l4 * 4 + r;
                *(unsigned short*)((char*)Ctx + tok * 528 + o * 2) = f2bf(ca[mtl][nt][r]);
            }
    }
    __syncthreads();

    // ---- Phase 5: out-proj: wave -> cout [16*nt2, +16), all 64 rows ----
    float4v oa[4];
#pragma unroll
    for (int mt = 0; mt < 4; ++mt) oa[mt] = (float4v){0.f, 0.f, 0.f, 0.f};
    const unsigned short* womat = wfrag + 3 * 65536;
#pragma unroll
    for (int ks = 0; ks < 8; ++ks) {
        short8 bfr = *(const short8*)(womat + ((ks * 16 + nt2) * 64 + l) * 8);
#pragma unroll
        for (int mt = 0; mt < 4; ++mt) {
            short8 afr = *(const short8*)((const char*)Ctx + (mt * 16 + l15) * 528 + (ks * 32 + l4 * 8) * 2);
            oa[mt] = __builtin_amdgcn_mfma_f32_16x16x32_bf16(afr, bfr, oa[mt], 0, 0, 0);
        }
    }
    // y = attn + bo + x(residual from bf16) -> Y fp32 [64][260]
    float* Y = (float*)(smem + Y_OFF);
    {
        const int cout = nt2 * 16 + l15;
        const float bias = bo[cout];
#pragma unroll
        for (int mt = 0; mt < 4; ++mt)
#pragma unroll
            for (int r = 0; r < 4; ++r) {
                const int tok = mt * 16 + l4 * 4 + r;
                const float xv = bf2f(Xbf[tok * 264 + cout]);
                Y[tok * 260 + cout] = oa[mt][r] + bias + xv;
            }
    }
    __syncthreads();

    // ---- Phase 6: LayerNorm per token (one token per wave) + rolled scatter store ----
    const float4v g4  = *(const float4v*)(gamma + l * 4);
    const float4v be4 = *(const float4v*)(beta + l * 4);
#pragma unroll
    for (int t = 0; t < 4; ++t) {
        const int tok = w + t * 16;
        if (tok < 49) {
            float4v f = *(const float4v*)(Y + tok * 260 + l * 4);
            float sum = f.x + f.y + f.z + f.w;
            float sq  = f.x * f.x + f.y * f.y + f.z * f.z + f.w * f.w;
#pragma unroll
            for (int msk = 1; msk < 64; msk <<= 1) {
                sum += __shfl_xor(sum, msk, 64);
                sq  += __shfl_xor(sq,  msk, 64);
            }
            const float mu   = sum * (1.f / 256.f);
            const float var  = sq * (1.f / 256.f) - mu * mu;
            const float rstd = rsqrtf(var + 1e-3f);
            const int i = tok / 7;
            const int j = tok - 7 * i;
            int gr = wh * 7 + i + 3; if (gr >= 112) gr -= 112;
            int gc = ww * 7 + j + 3; if (gc >= 112) gc -= 112;
            float4v o4;
            o4.x = (f.x - mu) * rstd * g4.x + be4.x;
            o4.y = (f.y - mu) * rstd * g4.y + be4.y;
            o4.z = (f.z - mu) * rstd * g4.z + be4.z;
            o4.w = (f.w - mu) * rstd * g4.w + be4.w;
            *(float4v*)(out + (((size_t)bb * 112 + gr) * 112 + gc) * 256 + l * 4) = o4;
        }
    }
}

extern "C" void kernel_launch(void* const* d_in, const int* in_sizes, int n_in,
                              void* d_out, int out_size, void* d_ws, size_t ws_size,
                              hipStream_t stream) {
    const float* x     = (const float*)d_in[0];
    const float* wq    = (const float*)d_in[1];
    const float* bq    = (const float*)d_in[2];
    const float* wk    = (const float*)d_in[3];
    const float* bk    = (const float*)d_in[4];
    const float* wv    = (const float*)d_in[5];
    const float* bv    = (const float*)d_in[6];
    const float* wo    = (const float*)d_in[7];
    const float* bo    = (const float*)d_in[8];
    const float* gamma = (const float*)d_in[9];
    const float* beta  = (const float*)d_in[10];
    float* out = (float*)d_out;
    unsigned short* wfrag = (unsigned short*)d_ws;   // 4 * 65536 bf16 = 512 KB

    prep_weights<<<1024, 256, 0, stream>>>(wq, wk, wv, wo, wfrag);

    hipFuncSetAttribute((const void*)swin_fused,
                        hipFuncAttributeMaxDynamicSharedMemorySize, LDS_BYTES);
    swin_fused<<<4096, 1024, LDS_BYTES, stream>>>(x, wfrag, bq, bk, bv, bo, gamma, beta, out);
}

// Round 4
// 302.789 us; speedup vs baseline: 1.5726x; 1.1023x over previous
//
#include <hip/hip_runtime.h>
#include <hip/hip_bf16.h>

typedef __attribute__((ext_vector_type(8))) short short8;
typedef __attribute__((ext_vector_type(4))) short short4v;
typedef __attribute__((ext_vector_type(4))) float float4v;

#define LDS_BYTES 144384
// LDS arena (bytes):
//  Xbf : [64][264] bf16 @ 0      (33792) — live whole kernel (residual)
//  Vt  : 8 x [32][72] bf16 @ 33792 (36864) — per-head V^T
//  Q   : [64][264] bf16 @ 70656  (33792)
//  K   : [64][264] bf16 @ 104448 (33792)
//  P   : 8 x [64][72] bf16 @ 70656 (73728)  — aliases Q+K after S done
//  CTX : [64][264] bf16 @ 33792  (33792)    — aliases Vt after PV done
//  Y   : [64][260] f32  @ 70656  (66560)    — aliases P after PV done
#define XBF_OFF   0
#define VT_OFF    33792
#define Q_OFF     70656
#define K_OFF     104448
#define P_OFF     70656
#define CTX_OFF   33792
#define Y_OFF     70656

__device__ __forceinline__ unsigned short f2bf(float f) {
    union { float f; unsigned int u; } v; v.f = f;
    unsigned int r = v.u + 0x7FFFu + ((v.u >> 16) & 1u);
    return (unsigned short)(r >> 16);
}
__device__ __forceinline__ float bf2f(unsigned short h) {
    union { unsigned int u; float f; } v; v.u = ((unsigned int)h) << 16;
    return v.f;
}

// Pre-convert weights fp32 -> bf16 in MFMA B-fragment order:
// elem index = ((ks*16 + nt2)*64 + lane)*8 + j ; c = ks*32 + (lane>>4)*8 + j ;
// o = nt2*16 + (lane&15) ; value = W[c*256 + o].
__global__ void prep_weights(const float* __restrict__ wq, const float* __restrict__ wk,
                             const float* __restrict__ wv, const float* __restrict__ wo,
                             unsigned short* __restrict__ wfrag) {
    int tid = blockIdx.x * 256 + threadIdx.x;
    if (tid >= 4 * 65536) return;
    int m = tid >> 16;
    int e = tid & 65535;
    int j = e & 7;
    int lane = (e >> 3) & 63;
    int nt2 = (e >> 9) & 15;
    int ks = e >> 13;
    int c = ks * 32 + (lane >> 4) * 8 + j;
    int o = nt2 * 16 + (lane & 15);
    const float* W = (m == 0) ? wq : (m == 1) ? wk : (m == 2) ? wv : wo;
    wfrag[tid] = f2bf(W[c * 256 + o]);
}

__global__ __launch_bounds__(1024, 4) void swin_fused(
    const float* __restrict__ x,
    const unsigned short* __restrict__ wfrag,
    const float* __restrict__ bq, const float* __restrict__ bk,
    const float* __restrict__ bv, const float* __restrict__ bo,
    const float* __restrict__ gamma, const float* __restrict__ beta,
    float* __restrict__ out)
{
    extern __shared__ char smem[];
    const int tid = threadIdx.x;
    const int w    = tid >> 6;    // wave id 0..15
    const int h    = w & 7;       // head
    const int half = w >> 3;      // token-half
    const int l   = tid & 63;
    const int l15 = l & 15;
    const int l4  = l >> 4;
    const int nt2 = 2 * h + half; // 16-col output group owned by this wave

    const int blk = blockIdx.x;
    const int bb  = blk >> 8;
    const int wh  = (blk >> 4) & 15;
    const int ww  = blk & 15;

    unsigned short* Xbf = (unsigned short*)(smem + XBF_OFF);

    // ---- Phase 0: stage X (fp32 -> bf16), shifted-window gather, rows 49..63 zero ----
    for (int idx = tid; idx < 64 * 64; idx += 1024) {
        const int tok = idx >> 6;
        const int c4  = idx & 63;
        float4v f = (float4v){0.f, 0.f, 0.f, 0.f};
        if (tok < 49) {
            const int i = tok / 7;
            const int j = tok - 7 * i;
            int gr = wh * 7 + i + 3; if (gr >= 112) gr -= 112;
            int gc = ww * 7 + j + 3; if (gc >= 112) gc -= 112;
            f = *(const float4v*)(x + (((size_t)bb * 112 + gr) * 112 + gc) * 256 + c4 * 4);
        }
        short4v hv;
        hv.x = (short)f2bf(f.x); hv.y = (short)f2bf(f.y);
        hv.z = (short)f2bf(f.z); hv.w = (short)f2bf(f.w);
        *(short4v*)(Xbf + tok * 264 + c4 * 4) = hv;
    }
    __syncthreads();

    unsigned short* Qs = (unsigned short*)(smem + Q_OFF);
    unsigned short* Ks = (unsigned short*)(smem + K_OFF);
    unsigned short* Vt = (unsigned short*)(smem + VT_OFF);

    // ---- Phase 1: QKV projection. Wave (h,half) -> output cols [16*nt2, +16) of each ----
    const float* biases[3] = { bq, bk, bv };
#pragma unroll
    for (int m = 0; m < 3; ++m) {
        float4v acc[4];
#pragma unroll
        for (int mt = 0; mt < 4; ++mt) acc[mt] = (float4v){0.f, 0.f, 0.f, 0.f};
        const unsigned short* wmat = wfrag + m * 65536;
#pragma unroll
        for (int ks = 0; ks < 8; ++ks) {
            short8 bfr = *(const short8*)(wmat + ((ks * 16 + nt2) * 64 + l) * 8);
#pragma unroll
            for (int mt = 0; mt < 4; ++mt) {
                short8 afr = *(const short8*)(Xbf + (mt * 16 + l15) * 264 + ks * 32 + l4 * 8);
                acc[mt] = __builtin_amdgcn_mfma_f32_16x16x32_bf16(afr, bfr, acc[mt], 0, 0, 0);
            }
        }
        const int o = nt2 * 16 + l15;
        const float bias = biases[m][o];
        if (m == 2) {
            const int d = half * 16 + l15;
#pragma unroll
            for (int mt = 0; mt < 4; ++mt) {
                short4v hv;
                hv.x = (short)f2bf(acc[mt][0] + bias);
                hv.y = (short)f2bf(acc[mt][1] + bias);
                hv.z = (short)f2bf(acc[mt][2] + bias);
                hv.w = (short)f2bf(acc[mt][3] + bias);
                *(short4v*)(Vt + h * 2304 + d * 72 + mt * 16 + l4 * 4) = hv;
            }
        } else {
            unsigned short* dst = (m == 0) ? Qs : Ks;
#pragma unroll
            for (int mt = 0; mt < 4; ++mt) {
                const int tok0 = mt * 16 + l4 * 4;
                dst[(tok0 + 0) * 264 + o] = f2bf(acc[mt][0] + bias);
                dst[(tok0 + 1) * 264 + o] = f2bf(acc[mt][1] + bias);
                dst[(tok0 + 2) * 264 + o] = f2bf(acc[mt][2] + bias);
                dst[(tok0 + 3) * 264 + o] = f2bf(acc[mt][3] + bias);
            }
        }
    }
    __syncthreads();   // cross-wave: S needs both halves' Q/K cols

    // ---- Phase 2: S^T = K Q^T. sa[mt][nt]: row k_tok = mt*16+l4*4+r, col q = 32*half+nt*16+l15 ----
    float4v sa[4][2];
#pragma unroll
    for (int mt = 0; mt < 4; ++mt)
#pragma unroll
        for (int nt = 0; nt < 2; ++nt)
            sa[mt][nt] = (float4v){0.f, 0.f, 0.f, 0.f};
    {
        short8 kfr[4], qfr[2];
#pragma unroll
        for (int mt = 0; mt < 4; ++mt)
            kfr[mt] = *(const short8*)(Ks + (mt * 16 + l15) * 264 + 32 * h + l4 * 8);
#pragma unroll
        for (int nt = 0; nt < 2; ++nt)
            qfr[nt] = *(const short8*)(Qs + (32 * half + nt * 16 + l15) * 264 + 32 * h + l4 * 8);
#pragma unroll
        for (int mt = 0; mt < 4; ++mt)
#pragma unroll
            for (int nt = 0; nt < 2; ++nt)
                sa[mt][nt] = __builtin_amdgcn_mfma_f32_16x16x32_bf16(kfr[mt], qfr[nt], sa[mt][nt], 0, 0, 0);
    }
    __syncthreads();   // all waves done reading Q/K before P overwrites them

    // ---- Phase 3: in-register softmax over k (per-lane 16 k-values, 4-lane-group reduce) ----
    unsigned short* Ph = (unsigned short*)(smem + P_OFF) + h * 4608;  // 9216 B / head
    const float SCALE = 0.17677669529663687f;  // 1/sqrt(32)
#pragma unroll
    for (int nt = 0; nt < 2; ++nt) {
        float sv[4][4];
        float mx = -1e30f;
#pragma unroll
        for (int mt = 0; mt < 4; ++mt)
#pragma unroll
            for (int r = 0; r < 4; ++r) {
                // k = mt*16 + l4*4 + r ; valid iff k < 49
                const bool valid = (mt < 3) || ((l4 == 0) && (r == 0));
                sv[mt][r] = valid ? sa[mt][nt][r] * SCALE : -1e30f;
                mx = fmaxf(mx, sv[mt][r]);
            }
        mx = fmaxf(mx, __shfl_xor(mx, 16, 64));
        mx = fmaxf(mx, __shfl_xor(mx, 32, 64));
        float p[4][4];
        float sum = 0.f;
#pragma unroll
        for (int mt = 0; mt < 4; ++mt)
#pragma unroll
            for (int r = 0; r < 4; ++r) {
                p[mt][r] = __expf(sv[mt][r] - mx);   // exp(-1e30 - mx) == 0, masks k>=49
                sum += p[mt][r];
            }
        sum += __shfl_xor(sum, 16, 64);
        sum += __shfl_xor(sum, 32, 64);
        const float inv = 1.f / sum;
        const int q = 32 * half + nt * 16 + l15;
#pragma unroll
        for (int mt = 0; mt < 4; ++mt) {
            short4v hv;
            hv.x = (short)f2bf(p[mt][0] * inv);
            hv.y = (short)f2bf(p[mt][1] * inv);
            hv.z = (short)f2bf(p[mt][2] * inv);
            hv.w = (short)f2bf(p[mt][3] * inv);
            *(short4v*)(Ph + q * 72 + mt * 16 + l4 * 4) = hv;
        }
    }
    // No barrier: PV reads only this wave's P rows and head-h Vt (covered by proj barrier).

    // ---- Phase 4: ctx rows [32*half,+32) = P V for head h ----
    float4v ca[2][2];
#pragma unroll
    for (int mtl = 0; mtl < 2; ++mtl)
#pragma unroll
        for (int nt = 0; nt < 2; ++nt)
            ca[mtl][nt] = (float4v){0.f, 0.f, 0.f, 0.f};
#pragma unroll
    for (int ks = 0; ks < 2; ++ks) {
        short8 afr[2];
#pragma unroll
        for (int mtl = 0; mtl < 2; ++mtl)
            afr[mtl] = *(const short8*)(Ph + (32 * half + mtl * 16 + l15) * 72 + ks * 32 + l4 * 8);
#pragma unroll
        for (int nt = 0; nt < 2; ++nt) {
            short8 bfr = *(const short8*)(Vt + h * 2304 + (nt * 16 + l15) * 72 + ks * 32 + l4 * 8);
#pragma unroll
            for (int mtl = 0; mtl < 2; ++mtl)
                ca[mtl][nt] = __builtin_amdgcn_mfma_f32_16x16x32_bf16(afr[mtl], bfr, ca[mtl][nt], 0, 0, 0);
        }
    }
    __syncthreads();   // all PV reads of Vt done before CTX overwrites it

    // ---- write ctx bf16 packed [64][264] ----
    unsigned short* Ctx = (unsigned short*)(smem + CTX_OFF);
#pragma unroll
    for (int nt = 0; nt < 2; ++nt) {
        const int o = 32 * h + nt * 16 + l15;
#pragma unroll
        for (int mtl = 0; mtl < 2; ++mtl) {
            const int tok0 = (2 * half + mtl) * 16 + l4 * 4;
            Ctx[(tok0 + 0) * 264 + o] = f2bf(ca[mtl][nt][0]);
            Ctx[(tok0 + 1) * 264 + o] = f2bf(ca[mtl][nt][1]);
            Ctx[(tok0 + 2) * 264 + o] = f2bf(ca[mtl][nt][2]);
            Ctx[(tok0 + 3) * 264 + o] = f2bf(ca[mtl][nt][3]);
        }
    }
    __syncthreads();

    // ---- Phase 5: out-proj: wave -> cout [16*nt2, +16), all 64 rows ----
    float4v oa[4];
#pragma unroll
    for (int mt = 0; mt < 4; ++mt) oa[mt] = (float4v){0.f, 0.f, 0.f, 0.f};
    const unsigned short* womat = wfrag + 3 * 65536;
#pragma unroll
    for (int ks = 0; ks < 8; ++ks) {
        short8 bfr = *(const short8*)(womat + ((ks * 16 + nt2) * 64 + l) * 8);
#pragma unroll
        for (int mt = 0; mt < 4; ++mt) {
            short8 afr = *(const short8*)(Ctx + (mt * 16 + l15) * 264 + ks * 32 + l4 * 8);
            oa[mt] = __builtin_amdgcn_mfma_f32_16x16x32_bf16(afr, bfr, oa[mt], 0, 0, 0);
        }
    }
    // y = attn + bo + x(residual from bf16) -> Y fp32 [64][260]
    float* Y = (float*)(smem + Y_OFF);
    {
        const int cout = nt2 * 16 + l15;
        const float bias = bo[cout];
#pragma unroll
        for (int mt = 0; mt < 4; ++mt)
#pragma unroll
            for (int r = 0; r < 4; ++r) {
                const int tok = mt * 16 + l4 * 4 + r;
                const float xv = bf2f(Xbf[tok * 264 + cout]);
                Y[tok * 260 + cout] = oa[mt][r] + bias + xv;
            }
    }
    __syncthreads();

    // ---- Phase 6: LayerNorm per token (one token per wave) + rolled scatter store ----
    const float4v g4  = *(const float4v*)(gamma + l * 4);
    const float4v be4 = *(const float4v*)(beta + l * 4);
#pragma unroll
    for (int t = 0; t < 4; ++t) {
        const int tok = w + t * 16;
        if (tok < 49) {
            float4v f = *(const float4v*)(Y + tok * 260 + l * 4);
            float sum = f.x + f.y + f.z + f.w;
            float sq  = f.x * f.x + f.y * f.y + f.z * f.z + f.w * f.w;
#pragma unroll
            for (int msk = 1; msk < 64; msk <<= 1) {
                sum += __shfl_xor(sum, msk, 64);
                sq  += __shfl_xor(sq,  msk, 64);
            }
            const float mu   = sum * (1.f / 256.f);
            const float var  = sq * (1.f / 256.f) - mu * mu;
            const float rstd = rsqrtf(var + 1e-3f);
            const int i = tok / 7;
            const int j = tok - 7 * i;
            int gr = wh * 7 + i + 3; if (gr >= 112) gr -= 112;
            int gc = ww * 7 + j + 3; if (gc >= 112) gc -= 112;
            float4v o4;
            o4.x = (f.x - mu) * rstd * g4.x + be4.x;
            o4.y = (f.y - mu) * rstd * g4.y + be4.y;
            o4.z = (f.z - mu) * rstd * g4.z + be4.z;
            o4.w = (f.w - mu) * rstd * g4.w + be4.w;
            *(float4v*)(out + (((size_t)bb * 112 + gr) * 112 + gc) * 256 + l * 4) = o4;
        }
    }
}

extern "C" void kernel_launch(void* const* d_in, const int* in_sizes, int n_in,
                              void* d_out, int out_size, void* d_ws, size_t ws_size,
                              hipStream_t stream) {
    const float* x     = (const float*)d_in[0];
    const float* wq    = (const float*)d_in[1];
    const float* bq    = (const float*)d_in[2];
    const float* wk    = (const float*)d_in[3];
    const float* bk    = (const float*)d_in[4];
    const float* wv    = (const float*)d_in[5];
    const float* bv    = (const float*)d_in[6];
    const float* wo    = (const float*)d_in[7];
    const float* bo    = (const float*)d_in[8];
    const float* gamma = (const float*)d_in[9];
    const float* beta  = (const float*)d_in[10];
    float* out = (float*)d_out;
    unsigned short* wfrag = (unsigned short*)d_ws;   // 4 * 65536 bf16 = 512 KB

    prep_weights<<<1024, 256, 0, stream>>>(wq, wk, wv, wo, wfrag);

    hipFuncSetAttribute((const void*)swin_fused,
                        hipFuncAttributeMaxDynamicSharedMemorySize, LDS_BYTES);
    swin_fused<<<4096, 1024, LDS_BYTES, stream>>>(x, wfrag, bq, bk, bv, bo, gamma, beta, out);
}

// Round 5
// 301.032 us; speedup vs baseline: 1.5818x; 1.0058x over previous
//
#include <hip/hip_runtime.h>
#include <hip/hip_bf16.h>

typedef __attribute__((ext_vector_type(8))) short short8;
typedef __attribute__((ext_vector_type(4))) short short4v;
typedef __attribute__((ext_vector_type(4))) float float4v;
typedef __attribute__((ext_vector_type(2))) unsigned int uint2v;

#define LDS_BYTES 144384
// LDS arena (bytes) — identical to R4:
//  Xbf : [64][264] bf16 @ 0      (33792) — live whole kernel (residual), XOR-swizzled
//  Vt  : 8 x [32][72] bf16 @ 33792 (36864) — per-head V^T (linear)
//  Q   : [64][264] bf16 @ 70656  (33792) — XOR-swizzled
//  K   : [64][264] bf16 @ 104448 (33792) — XOR-swizzled
//  P   : 8 x [64][72] bf16 @ 70656 (73728)  — aliases Q+K after S done (linear)
//  CTX : [64][264] bf16 @ 33792  (33792)    — aliases Vt after PV done, XOR-swizzled
//  Y   : [64][260] f32  @ 70656  (66560)    — aliases P after PV done (linear)
#define XBF_OFF   0
#define VT_OFF    33792
#define Q_OFF     70656
#define K_OFF     104448
#define P_OFF     70656
#define CTX_OFF   33792
#define Y_OFF     70656

// Swizzle: byte ^= ((row & 8) << 2). Breaks the 4*528 ≡ 16 (mod 32-dword) aliasing
// between quarter-waves on scalar stores; preserves 16B alignment for b128 reads.

__device__ __forceinline__ unsigned short f2bf_rn(float f) {
    union { __hip_bfloat16 b; unsigned short u; } v;
    v.b = __float2bfloat16(f);
    return v.u;
}
__device__ __forceinline__ unsigned int pk2bf(float a, float b) {
    union { __hip_bfloat162 h; unsigned int u; } v;
    v.h = __float22bfloat162_rn(make_float2(a, b));
    return v.u;
}
__device__ __forceinline__ float bf2f(unsigned short h) {
    union { unsigned int u; float f; } v; v.u = ((unsigned int)h) << 16;
    return v.f;
}

// Pre-convert weights fp32 -> bf16 in MFMA B-fragment order:
// elem index = ((ks*16 + nt2)*64 + lane)*8 + j ; c = ks*32 + (lane>>4)*8 + j ;
// o = nt2*16 + (lane&15) ; value = W[c*256 + o].
__global__ void prep_weights(const float* __restrict__ wq, const float* __restrict__ wk,
                             const float* __restrict__ wv, const float* __restrict__ wo,
                             unsigned short* __restrict__ wfrag) {
    int tid = blockIdx.x * 256 + threadIdx.x;
    if (tid >= 4 * 65536) return;
    int m = tid >> 16;
    int e = tid & 65535;
    int j = e & 7;
    int lane = (e >> 3) & 63;
    int nt2 = (e >> 9) & 15;
    int ks = e >> 13;
    int c = ks * 32 + (lane >> 4) * 8 + j;
    int o = nt2 * 16 + (lane & 15);
    const float* W = (m == 0) ? wq : (m == 1) ? wk : (m == 2) ? wv : wo;
    wfrag[tid] = f2bf_rn(W[c * 256 + o]);
}

__global__ __launch_bounds__(1024, 4) void swin_fused(
    const float* __restrict__ x,
    const unsigned short* __restrict__ wfrag,
    const float* __restrict__ bq, const float* __restrict__ bk,
    const float* __restrict__ bv, const float* __restrict__ bo,
    const float* __restrict__ gamma, const float* __restrict__ beta,
    float* __restrict__ out)
{
    extern __shared__ char smem[];
    const int tid = threadIdx.x;
    const int w    = tid >> 6;    // wave id 0..15
    const int h    = w & 7;       // head
    const int half = w >> 3;      // token-half
    const int l   = tid & 63;
    const int l15 = l & 15;
    const int l4  = l >> 4;
    const int nt2 = 2 * h + half; // 16-col output group owned by this wave

    // Swizzle XOR terms (thread-invariant per access pattern):
    const int sxA = (l15 & 8) << 2;  // b128 frag reads: row = ...*16 + l15
    const int sxS = (l4  & 2) << 4;  // scalar stores / residual reads: row = ...*16 + l4*4 + r

    const int blk = blockIdx.x;
    const int bb  = blk >> 8;
    const int wh  = (blk >> 4) & 15;
    const int ww  = blk & 15;

    char* XbfC = smem + XBF_OFF;

    // ---- Phase 0: stage X (fp32 -> bf16), shifted-window gather, rows 49..63 zero ----
    for (int idx = tid; idx < 64 * 64; idx += 1024) {
        const int tok = idx >> 6;
        const int c4  = idx & 63;
        float4v f = (float4v){0.f, 0.f, 0.f, 0.f};
        if (tok < 49) {
            const int i = tok / 7;
            const int j = tok - 7 * i;
            int gr = wh * 7 + i + 3; if (gr >= 112) gr -= 112;
            int gc = ww * 7 + j + 3; if (gc >= 112) gc -= 112;
            f = *(const float4v*)(x + (((size_t)bb * 112 + gr) * 112 + gc) * 256 + c4 * 4);
        }
        uint2v u;
        u.x = pk2bf(f.x, f.y);
        u.y = pk2bf(f.z, f.w);
        *(uint2v*)(XbfC + ((tok * 528 + c4 * 8) ^ ((tok & 8) << 2))) = u;
    }
    __syncthreads();

    char* QsC = smem + Q_OFF;
    char* KsC = smem + K_OFF;
    unsigned short* Vt = (unsigned short*)(smem + VT_OFF);

    // ---- Phase 1: QKV projection. Wave (h,half) -> output cols [16*nt2, +16) of each ----
    const float* biases[3] = { bq, bk, bv };
#pragma unroll
    for (int m = 0; m < 3; ++m) {
        float4v acc[4];
#pragma unroll
        for (int mt = 0; mt < 4; ++mt) acc[mt] = (float4v){0.f, 0.f, 0.f, 0.f};
        const unsigned short* wmat = wfrag + m * 65536;
        __builtin_amdgcn_s_setprio(1);
#pragma unroll
        for (int ks = 0; ks < 8; ++ks) {
            short8 bfr = *(const short8*)(wmat + ((ks * 16 + nt2) * 64 + l) * 8);
#pragma unroll
            for (int mt = 0; mt < 4; ++mt) {
                short8 afr = *(const short8*)(XbfC + (((mt * 16 + l15) * 528 + (ks * 32 + l4 * 8) * 2) ^ sxA));
                acc[mt] = __builtin_amdgcn_mfma_f32_16x16x32_bf16(afr, bfr, acc[mt], 0, 0, 0);
            }
        }
        __builtin_amdgcn_s_setprio(0);
        const int o = nt2 * 16 + l15;
        const float bias = biases[m][o];
        if (m == 2) {
            const int d = half * 16 + l15;
#pragma unroll
            for (int mt = 0; mt < 4; ++mt) {
                uint2v u;
                u.x = pk2bf(acc[mt][0] + bias, acc[mt][1] + bias);
                u.y = pk2bf(acc[mt][2] + bias, acc[mt][3] + bias);
                *(uint2v*)(Vt + h * 2304 + d * 72 + mt * 16 + l4 * 4) = u;
            }
        } else {
            char* dst = (m == 0) ? QsC : KsC;
#pragma unroll
            for (int mt = 0; mt < 4; ++mt) {
                const int tok0 = mt * 16 + l4 * 4;
#pragma unroll
                for (int r = 0; r < 4; ++r)
                    *(unsigned short*)(dst + (((tok0 + r) * 528 + o * 2) ^ sxS)) = f2bf_rn(acc[mt][r] + bias);
            }
        }
    }
    __syncthreads();   // cross-wave: S needs both halves' Q/K cols

    // ---- Phase 2: S^T = K Q^T. sa[mt][nt]: row k_tok = mt*16+l4*4+r, col q = 32*half+nt*16+l15 ----
    float4v sa[4][2];
#pragma unroll
    for (int mt = 0; mt < 4; ++mt)
#pragma unroll
        for (int nt = 0; nt < 2; ++nt)
            sa[mt][nt] = (float4v){0.f, 0.f, 0.f, 0.f};
    {
        short8 kfr[4], qfr[2];
#pragma unroll
        for (int mt = 0; mt < 4; ++mt)
            kfr[mt] = *(const short8*)(KsC + (((mt * 16 + l15) * 528 + (32 * h + l4 * 8) * 2) ^ sxA));
#pragma unroll
        for (int nt = 0; nt < 2; ++nt)
            qfr[nt] = *(const short8*)(QsC + (((32 * half + nt * 16 + l15) * 528 + (32 * h + l4 * 8) * 2) ^ sxA));
        __builtin_amdgcn_s_setprio(1);
#pragma unroll
        for (int mt = 0; mt < 4; ++mt)
#pragma unroll
            for (int nt = 0; nt < 2; ++nt)
                sa[mt][nt] = __builtin_amdgcn_mfma_f32_16x16x32_bf16(kfr[mt], qfr[nt], sa[mt][nt], 0, 0, 0);
        __builtin_amdgcn_s_setprio(0);
    }
    __syncthreads();   // all waves done reading Q/K before P overwrites them

    // ---- Phase 3: in-register softmax over k (per-lane 16 k-values, 4-lane-group reduce) ----
    unsigned short* Ph = (unsigned short*)(smem + P_OFF) + h * 4608;  // 9216 B / head
    const float SCALE = 0.17677669529663687f;  // 1/sqrt(32)
#pragma unroll
    for (int nt = 0; nt < 2; ++nt) {
        float sv[4][4];
        float mx = -1e30f;
#pragma unroll
        for (int mt = 0; mt < 4; ++mt)
#pragma unroll
            for (int r = 0; r < 4; ++r) {
                // k = mt*16 + l4*4 + r ; valid iff k < 49
                const bool valid = (mt < 3) || ((l4 == 0) && (r == 0));
                sv[mt][r] = valid ? sa[mt][nt][r] * SCALE : -1e30f;
                mx = fmaxf(mx, sv[mt][r]);
            }
        mx = fmaxf(mx, __shfl_xor(mx, 16, 64));
        mx = fmaxf(mx, __shfl_xor(mx, 32, 64));
        float p[4][4];
        float sum = 0.f;
#pragma unroll
        for (int mt = 0; mt < 4; ++mt)
#pragma unroll
            for (int r = 0; r < 4; ++r) {
                p[mt][r] = __expf(sv[mt][r] - mx);   // exp(-1e30 - mx) == 0, masks k>=49
                sum += p[mt][r];
            }
        sum += __shfl_xor(sum, 16, 64);
        sum += __shfl_xor(sum, 32, 64);
        const float inv = 1.f / sum;
        const int q = 32 * half + nt * 16 + l15;
#pragma unroll
        for (int mt = 0; mt < 4; ++mt) {
            uint2v u;
            u.x = pk2bf(p[mt][0] * inv, p[mt][1] * inv);
            u.y = pk2bf(p[mt][2] * inv, p[mt][3] * inv);
            *(uint2v*)(Ph + q * 72 + mt * 16 + l4 * 4) = u;
        }
    }
    // No barrier: PV reads only this wave's P rows and head-h Vt (covered by proj barrier).

    // ---- Phase 4: ctx rows [32*half,+32) = P V for head h ----
    float4v ca[2][2];
#pragma unroll
    for (int mtl = 0; mtl < 2; ++mtl)
#pragma unroll
        for (int nt = 0; nt < 2; ++nt)
            ca[mtl][nt] = (float4v){0.f, 0.f, 0.f, 0.f};
#pragma unroll
    for (int ks = 0; ks < 2; ++ks) {
        short8 afr[2];
#pragma unroll
        for (int mtl = 0; mtl < 2; ++mtl)
            afr[mtl] = *(const short8*)(Ph + (32 * half + mtl * 16 + l15) * 72 + ks * 32 + l4 * 8);
        __builtin_amdgcn_s_setprio(1);
#pragma unroll
        for (int nt = 0; nt < 2; ++nt) {
            short8 bfr = *(const short8*)(Vt + h * 2304 + (nt * 16 + l15) * 72 + ks * 32 + l4 * 8);
#pragma unroll
            for (int mtl = 0; mtl < 2; ++mtl)
                ca[mtl][nt] = __builtin_amdgcn_mfma_f32_16x16x32_bf16(afr[mtl], bfr, ca[mtl][nt], 0, 0, 0);
        }
        __builtin_amdgcn_s_setprio(0);
    }
    __syncthreads();   // all PV reads of Vt done before CTX overwrites it

    // ---- write ctx bf16 packed [64][264] (XOR-swizzled) ----
    char* CtxC = smem + CTX_OFF;
#pragma unroll
    for (int nt = 0; nt < 2; ++nt) {
        const int o = 32 * h + nt * 16 + l15;
#pragma unroll
        for (int mtl = 0; mtl < 2; ++mtl) {
            const int tok0 = (2 * half + mtl) * 16 + l4 * 4;
#pragma unroll
            for (int r = 0; r < 4; ++r)
                *(unsigned short*)(CtxC + (((tok0 + r) * 528 + o * 2) ^ sxS)) = f2bf_rn(ca[mtl][nt][r]);
        }
    }
    __syncthreads();

    // ---- Phase 5: out-proj: wave -> cout [16*nt2, +16), all 64 rows ----
    float4v oa[4];
#pragma unroll
    for (int mt = 0; mt < 4; ++mt) oa[mt] = (float4v){0.f, 0.f, 0.f, 0.f};
    const unsigned short* womat = wfrag + 3 * 65536;
    __builtin_amdgcn_s_setprio(1);
#pragma unroll
    for (int ks = 0; ks < 8; ++ks) {
        short8 bfr = *(const short8*)(womat + ((ks * 16 + nt2) * 64 + l) * 8);
#pragma unroll
        for (int mt = 0; mt < 4; ++mt) {
            short8 afr = *(const short8*)(CtxC + (((mt * 16 + l15) * 528 + (ks * 32 + l4 * 8) * 2) ^ sxA));
            oa[mt] = __builtin_amdgcn_mfma_f32_16x16x32_bf16(afr, bfr, oa[mt], 0, 0, 0);
        }
    }
    __builtin_amdgcn_s_setprio(0);
    // y = attn + bo + x(residual from bf16) -> Y fp32 [64][260]
    float* Y = (float*)(smem + Y_OFF);
    {
        const int cout = nt2 * 16 + l15;
        const float bias = bo[cout];
#pragma unroll
        for (int mt = 0; mt < 4; ++mt)
#pragma unroll
            for (int r = 0; r < 4; ++r) {
                const int tok = mt * 16 + l4 * 4 + r;
                const float xv = bf2f(*(const unsigned short*)(XbfC + ((tok * 528 + cout * 2) ^ sxS)));
                Y[tok * 260 + cout] = oa[mt][r] + bias + xv;
            }
    }
    __syncthreads();

    // ---- Phase 6: LayerNorm per token (one token per wave) + rolled scatter store ----
    const float4v g4  = *(const float4v*)(gamma + l * 4);
    const float4v be4 = *(const float4v*)(beta + l * 4);
#pragma unroll
    for (int t = 0; t < 4; ++t) {
        const int tok = w + t * 16;
        if (tok < 49) {
            float4v f = *(const float4v*)(Y + tok * 260 + l * 4);
            float sum = f.x + f.y + f.z + f.w;
            float sq  = f.x * f.x + f.y * f.y + f.z * f.z + f.w * f.w;
#pragma unroll
            for (int msk = 1; msk < 64; msk <<= 1) {
                sum += __shfl_xor(sum, msk, 64);
                sq  += __shfl_xor(sq,  msk, 64);
            }
            const float mu   = sum * (1.f / 256.f);
            const float var  = sq * (1.f / 256.f) - mu * mu;
            const float rstd = rsqrtf(var + 1e-3f);
            const int i = tok / 7;
            const int j = tok - 7 * i;
            int gr = wh * 7 + i + 3; if (gr >= 112) gr -= 112;
            int gc = ww * 7 + j + 3; if (gc >= 112) gc -= 112;
            float4v o4;
            o4.x = (f.x - mu) * rstd * g4.x + be4.x;
            o4.y = (f.y - mu) * rstd * g4.y + be4.y;
            o4.z = (f.z - mu) * rstd * g4.z + be4.z;
            o4.w = (f.w - mu) * rstd * g4.w + be4.w;
            *(float4v*)(out + (((size_t)bb * 112 + gr) * 112 + gc) * 256 + l * 4) = o4;
        }
    }
}

extern "C" void kernel_launch(void* const* d_in, const int* in_sizes, int n_in,
                              void* d_out, int out_size, void* d_ws, size_t ws_size,
                              hipStream_t stream) {
    const float* x     = (const float*)d_in[0];
    const float* wq    = (const float*)d_in[1];
    const float* bq    = (const float*)d_in[2];
    const float* wk    = (const float*)d_in[3];
    const float* bk    = (const float*)d_in[4];
    const float* wv    = (const float*)d_in[5];
    const float* bv    = (const float*)d_in[6];
    const float* wo    = (const float*)d_in[7];
    const float* bo    = (const float*)d_in[8];
    const float* gamma = (const float*)d_in[9];
    const float* beta  = (const float*)d_in[10];
    float* out = (float*)d_out;
    unsigned short* wfrag = (unsigned short*)d_ws;   // 4 * 65536 bf16 = 512 KB

    prep_weights<<<1024, 256, 0, stream>>>(wq, wk, wv, wo, wfrag);

    hipFuncSetAttribute((const void*)swin_fused,
                        hipFuncAttributeMaxDynamicSharedMemorySize, LDS_BYTES);
    swin_fused<<<4096, 1024, LDS_BYTES, stream>>>(x, wfrag, bq, bk, bv, bo, gamma, beta, out);
}

// Round 6
// 277.574 us; speedup vs baseline: 1.7154x; 1.0845x over previous
//
#include <hip/hip_runtime.h>
#include <hip/hip_bf16.h>

typedef __attribute__((ext_vector_type(8))) short short8;
typedef __attribute__((ext_vector_type(4))) short short4v;
typedef __attribute__((ext_vector_type(4))) float float4v;
typedef __attribute__((ext_vector_type(2))) unsigned int uint2v;

#define LDS_BYTES 144384
// LDS arena (bytes):
//  Xbf : [64][264] bf16 @ 0      (33792) — live whole kernel (residual)
//  Vt  : 8 x [32][72] bf16 @ 33792 (36864) — per-head V^T
//  Q   : [64][264] bf16 @ 70656  (33792)
//  K   : [64][264] bf16 @ 104448 (33792)
//  P   : 8 x [64][72] bf16 @ 70656 (73728)  — aliases Q+K after S done
//  CTX : [64][264] bf16 @ 33792  (33792)    — aliases Vt after PV done
//  Y   : [64][260] f32  @ 70656  (66560)    — aliases P after PV done
#define XBF_OFF   0
#define VT_OFF    33792
#define Q_OFF     70656
#define K_OFF     104448
#define P_OFF     70656
#define CTX_OFF   33792
#define Y_OFF     70656

__device__ __forceinline__ unsigned short f2bf_rn(float f) {
    union { __hip_bfloat16 b; unsigned short u; } v;
    v.b = __float2bfloat16(f);
    return v.u;
}
__device__ __forceinline__ unsigned int pk2bf(float a, float b) {
    union { __hip_bfloat162 h; unsigned int u; } v;
    v.h = __float22bfloat162_rn(make_float2(a, b));
    return v.u;
}
__device__ __forceinline__ float bf2f(unsigned short h) {
    union { unsigned int u; float f; } v; v.u = ((unsigned int)h) << 16;
    return v.f;
}

// Pre-convert weights fp32 -> bf16 in MFMA B-fragment order:
// elem index = ((ks*16 + nt2)*64 + lane)*8 + j ; c = ks*32 + (lane>>4)*8 + j ;
// o = nt2*16 + (lane&15) ; value = W[c*256 + o].
__global__ void prep_weights(const float* __restrict__ wq, const float* __restrict__ wk,
                             const float* __restrict__ wv, const float* __restrict__ wo,
                             unsigned short* __restrict__ wfrag) {
    int tid = blockIdx.x * 256 + threadIdx.x;
    if (tid >= 4 * 65536) return;
    int m = tid >> 16;
    int e = tid & 65535;
    int j = e & 7;
    int lane = (e >> 3) & 63;
    int nt2 = (e >> 9) & 15;
    int ks = e >> 13;
    int c = ks * 32 + (lane >> 4) * 8 + j;
    int o = nt2 * 16 + (lane & 15);
    const float* W = (m == 0) ? wq : (m == 1) ? wk : (m == 2) ? wv : wo;
    wfrag[tid] = f2bf_rn(W[c * 256 + o]);
}

__global__ __launch_bounds__(1024, 4) void swin_fused(
    const float* __restrict__ x,
    const unsigned short* __restrict__ wfrag,
    const float* __restrict__ bq, const float* __restrict__ bk,
    const float* __restrict__ bv, const float* __restrict__ bo,
    const float* __restrict__ gamma, const float* __restrict__ beta,
    float* __restrict__ out)
{
    extern __shared__ char smem[];
    const int tid = threadIdx.x;
    const int w    = tid >> 6;    // wave id 0..15
    const int h    = w & 7;       // head
    const int half = w >> 3;      // token-half
    const int l   = tid & 63;
    const int l15 = l & 15;
    const int l4  = l >> 4;
    const int nt2 = 2 * h + half; // 16-col output group owned by this wave

    const int blk = blockIdx.x;
    const int bb  = blk >> 8;
    const int wh  = (blk >> 4) & 15;
    const int ww  = blk & 15;

    unsigned short* Xbf = (unsigned short*)(smem + XBF_OFF);

    // ---- Phase 0: stage X (fp32 -> bf16), shifted-window gather, rows 49..63 zero ----
    for (int idx = tid; idx < 64 * 64; idx += 1024) {
        const int tok = idx >> 6;
        const int c4  = idx & 63;
        float4v f = (float4v){0.f, 0.f, 0.f, 0.f};
        if (tok < 49) {
            const int i = tok / 7;
            const int j = tok - 7 * i;
            int gr = wh * 7 + i + 3; if (gr >= 112) gr -= 112;
            int gc = ww * 7 + j + 3; if (gc >= 112) gc -= 112;
            f = *(const float4v*)(x + (((size_t)bb * 112 + gr) * 112 + gc) * 256 + c4 * 4);
        }
        uint2v u;
        u.x = pk2bf(f.x, f.y);
        u.y = pk2bf(f.z, f.w);
        *(uint2v*)(Xbf + tok * 264 + c4 * 4) = u;
    }
    __syncthreads();

    unsigned short* Qs = (unsigned short*)(smem + Q_OFF);
    unsigned short* Ks = (unsigned short*)(smem + K_OFF);
    unsigned short* Vt = (unsigned short*)(smem + VT_OFF);

    // ---- Phase 1: QKV projection, ks-outer so each X A-fragment is read ONCE and
    //      reused for Q, K and V (A-frag b128 reads: 96 -> 32 per wave) ----
    {
        float4v accQ[4], accK[4], accV[4];
#pragma unroll
        for (int mt = 0; mt < 4; ++mt) {
            accQ[mt] = (float4v){0.f, 0.f, 0.f, 0.f};
            accK[mt] = (float4v){0.f, 0.f, 0.f, 0.f};
            accV[mt] = (float4v){0.f, 0.f, 0.f, 0.f};
        }
        const unsigned short* wqf = wfrag;
        const unsigned short* wkf = wfrag + 65536;
        const unsigned short* wvf = wfrag + 2 * 65536;
#pragma unroll
        for (int ks = 0; ks < 8; ++ks) {
            const int woff = ((ks * 16 + nt2) * 64 + l) * 8;
            short8 bq_ = *(const short8*)(wqf + woff);
            short8 bk_ = *(const short8*)(wkf + woff);
            short8 bv_ = *(const short8*)(wvf + woff);
            short8 afr[4];
#pragma unroll
            for (int mt = 0; mt < 4; ++mt)
                afr[mt] = *(const short8*)(Xbf + (mt * 16 + l15) * 264 + ks * 32 + l4 * 8);
            __builtin_amdgcn_s_setprio(1);
#pragma unroll
            for (int mt = 0; mt < 4; ++mt)
                accQ[mt] = __builtin_amdgcn_mfma_f32_16x16x32_bf16(afr[mt], bq_, accQ[mt], 0, 0, 0);
#pragma unroll
            for (int mt = 0; mt < 4; ++mt)
                accK[mt] = __builtin_amdgcn_mfma_f32_16x16x32_bf16(afr[mt], bk_, accK[mt], 0, 0, 0);
#pragma unroll
            for (int mt = 0; mt < 4; ++mt)
                accV[mt] = __builtin_amdgcn_mfma_f32_16x16x32_bf16(afr[mt], bv_, accV[mt], 0, 0, 0);
            __builtin_amdgcn_s_setprio(0);
        }
        const int o = nt2 * 16 + l15;
        const float biasq = bq[o];
        const float biask = bk[o];
        const float biasv = bv[o];
        // Q, K: [64][264] scalar b16 stores (column o)
#pragma unroll
        for (int mt = 0; mt < 4; ++mt) {
            const int tok0 = mt * 16 + l4 * 4;
#pragma unroll
            for (int r = 0; r < 4; ++r) {
                Qs[(tok0 + r) * 264 + o] = f2bf_rn(accQ[mt][r] + biasq);
                Ks[(tok0 + r) * 264 + o] = f2bf_rn(accK[mt][r] + biask);
            }
        }
        // V: transposed per head [32 d][72 tok], vector b64 stores
        const int d = half * 16 + l15;
#pragma unroll
        for (int mt = 0; mt < 4; ++mt) {
            uint2v u;
            u.x = pk2bf(accV[mt][0] + biasv, accV[mt][1] + biasv);
            u.y = pk2bf(accV[mt][2] + biasv, accV[mt][3] + biasv);
            *(uint2v*)(Vt + h * 2304 + d * 72 + mt * 16 + l4 * 4) = u;
        }
    }
    __syncthreads();   // cross-wave: S needs both halves' Q/K cols

    // ---- Phase 2: S^T = K Q^T. sa[mt][nt]: row k_tok = mt*16+l4*4+r, col q = 32*half+nt*16+l15 ----
    float4v sa[4][2];
#pragma unroll
    for (int mt = 0; mt < 4; ++mt)
#pragma unroll
        for (int nt = 0; nt < 2; ++nt)
            sa[mt][nt] = (float4v){0.f, 0.f, 0.f, 0.f};
    {
        short8 kfr[4], qfr[2];
#pragma unroll
        for (int mt = 0; mt < 4; ++mt)
            kfr[mt] = *(const short8*)(Ks + (mt * 16 + l15) * 264 + 32 * h + l4 * 8);
#pragma unroll
        for (int nt = 0; nt < 2; ++nt)
            qfr[nt] = *(const short8*)(Qs + (32 * half + nt * 16 + l15) * 264 + 32 * h + l4 * 8);
        __builtin_amdgcn_s_setprio(1);
#pragma unroll
        for (int mt = 0; mt < 4; ++mt)
#pragma unroll
            for (int nt = 0; nt < 2; ++nt)
                sa[mt][nt] = __builtin_amdgcn_mfma_f32_16x16x32_bf16(kfr[mt], qfr[nt], sa[mt][nt], 0, 0, 0);
        __builtin_amdgcn_s_setprio(0);
    }
    __syncthreads();   // all waves done reading Q/K before P overwrites them

    // ---- Phase 3: in-register softmax over k (per-lane 16 k-values, 4-lane-group reduce) ----
    unsigned short* Ph = (unsigned short*)(smem + P_OFF) + h * 4608;  // 9216 B / head
    const float SCALE = 0.17677669529663687f;  // 1/sqrt(32)
#pragma unroll
    for (int nt = 0; nt < 2; ++nt) {
        float sv[4][4];
        float mx = -1e30f;
#pragma unroll
        for (int mt = 0; mt < 4; ++mt)
#pragma unroll
            for (int r = 0; r < 4; ++r) {
                // k = mt*16 + l4*4 + r ; valid iff k < 49
                const bool valid = (mt < 3) || ((l4 == 0) && (r == 0));
                sv[mt][r] = valid ? sa[mt][nt][r] * SCALE : -1e30f;
                mx = fmaxf(mx, sv[mt][r]);
            }
        mx = fmaxf(mx, __shfl_xor(mx, 16, 64));
        mx = fmaxf(mx, __shfl_xor(mx, 32, 64));
        float p[4][4];
        float sum = 0.f;
#pragma unroll
        for (int mt = 0; mt < 4; ++mt)
#pragma unroll
            for (int r = 0; r < 4; ++r) {
                p[mt][r] = __expf(sv[mt][r] - mx);   // exp(-1e30 - mx) == 0, masks k>=49
                sum += p[mt][r];
            }
        sum += __shfl_xor(sum, 16, 64);
        sum += __shfl_xor(sum, 32, 64);
        const float inv = 1.f / sum;
        const int q = 32 * half + nt * 16 + l15;
#pragma unroll
        for (int mt = 0; mt < 4; ++mt) {
            uint2v u;
            u.x = pk2bf(p[mt][0] * inv, p[mt][1] * inv);
            u.y = pk2bf(p[mt][2] * inv, p[mt][3] * inv);
            *(uint2v*)(Ph + q * 72 + mt * 16 + l4 * 4) = u;
        }
    }
    // No barrier: PV reads only this wave's P rows and head-h Vt (covered by proj barrier).

    // ---- Phase 4: ctx rows [32*half,+32) = P V for head h ----
    float4v ca[2][2];
#pragma unroll
    for (int mtl = 0; mtl < 2; ++mtl)
#pragma unroll
        for (int nt = 0; nt < 2; ++nt)
            ca[mtl][nt] = (float4v){0.f, 0.f, 0.f, 0.f};
#pragma unroll
    for (int ks = 0; ks < 2; ++ks) {
        short8 afr[2];
#pragma unroll
        for (int mtl = 0; mtl < 2; ++mtl)
            afr[mtl] = *(const short8*)(Ph + (32 * half + mtl * 16 + l15) * 72 + ks * 32 + l4 * 8);
        __builtin_amdgcn_s_setprio(1);
#pragma unroll
        for (int nt = 0; nt < 2; ++nt) {
            short8 bfr = *(const short8*)(Vt + h * 2304 + (nt * 16 + l15) * 72 + ks * 32 + l4 * 8);
#pragma unroll
            for (int mtl = 0; mtl < 2; ++mtl)
                ca[mtl][nt] = __builtin_amdgcn_mfma_f32_16x16x32_bf16(afr[mtl], bfr, ca[mtl][nt], 0, 0, 0);
        }
        __builtin_amdgcn_s_setprio(0);
    }
    __syncthreads();   // all PV reads of Vt done before CTX overwrites it

    // ---- write ctx bf16 packed [64][264] ----
    unsigned short* Ctx = (unsigned short*)(smem + CTX_OFF);
#pragma unroll
    for (int nt = 0; nt < 2; ++nt) {
        const int o = 32 * h + nt * 16 + l15;
#pragma unroll
        for (int mtl = 0; mtl < 2; ++mtl) {
            const int tok0 = (2 * half + mtl) * 16 + l4 * 4;
            Ctx[(tok0 + 0) * 264 + o] = f2bf_rn(ca[mtl][nt][0]);
            Ctx[(tok0 + 1) * 264 + o] = f2bf_rn(ca[mtl][nt][1]);
            Ctx[(tok0 + 2) * 264 + o] = f2bf_rn(ca[mtl][nt][2]);
            Ctx[(tok0 + 3) * 264 + o] = f2bf_rn(ca[mtl][nt][3]);
        }
    }
    __syncthreads();

    // ---- Phase 5: out-proj: wave -> cout [16*nt2, +16), all 64 rows ----
    float4v oa[4];
#pragma unroll
    for (int mt = 0; mt < 4; ++mt) oa[mt] = (float4v){0.f, 0.f, 0.f, 0.f};
    const unsigned short* womat = wfrag + 3 * 65536;
#pragma unroll
    for (int ks = 0; ks < 8; ++ks) {
        short8 bfr = *(const short8*)(womat + ((ks * 16 + nt2) * 64 + l) * 8);
        short8 afr[4];
#pragma unroll
        for (int mt = 0; mt < 4; ++mt)
            afr[mt] = *(const short8*)(Ctx + (mt * 16 + l15) * 264 + ks * 32 + l4 * 8);
        __builtin_amdgcn_s_setprio(1);
#pragma unroll
        for (int mt = 0; mt < 4; ++mt)
            oa[mt] = __builtin_amdgcn_mfma_f32_16x16x32_bf16(afr[mt], bfr, oa[mt], 0, 0, 0);
        __builtin_amdgcn_s_setprio(0);
    }
    // y = attn + bo -> Y fp32 [64][260] (residual added in LN phase from Xbf rows)
    float* Y = (float*)(smem + Y_OFF);
    {
        const int cout = nt2 * 16 + l15;
        const float bias = bo[cout];
#pragma unroll
        for (int mt = 0; mt < 4; ++mt)
#pragma unroll
            for (int r = 0; r < 4; ++r) {
                const int tok = mt * 16 + l4 * 4 + r;
                Y[tok * 260 + cout] = oa[mt][r] + bias;
            }
    }
    __syncthreads();

    // ---- Phase 6: LayerNorm per token (one token per wave), residual from Xbf row, rolled scatter store ----
    const float4v g4  = *(const float4v*)(gamma + l * 4);
    const float4v be4 = *(const float4v*)(beta + l * 4);
#pragma unroll
    for (int t = 0; t < 4; ++t) {
        const int tok = w + t * 16;
        if (tok < 49) {
            float4v f = *(const float4v*)(Y + tok * 260 + l * 4);
            short4v xr = *(const short4v*)(Xbf + tok * 264 + l * 4);
            f.x += bf2f((unsigned short)xr.x);
            f.y += bf2f((unsigned short)xr.y);
            f.z += bf2f((unsigned short)xr.z);
            f.w += bf2f((unsigned short)xr.w);
            float sum = f.x + f.y + f.z + f.w;
            float sq  = f.x * f.x + f.y * f.y + f.z * f.z + f.w * f.w;
#pragma unroll
            for (int msk = 1; msk < 64; msk <<= 1) {
                sum += __shfl_xor(sum, msk, 64);
                sq  += __shfl_xor(sq,  msk, 64);
            }
            const float mu   = sum * (1.f / 256.f);
            const float var  = sq * (1.f / 256.f) - mu * mu;
            const float rstd = rsqrtf(var + 1e-3f);
            const int i = tok / 7;
            const int j = tok - 7 * i;
            int gr = wh * 7 + i + 3; if (gr >= 112) gr -= 112;
            int gc = ww * 7 + j + 3; if (gc >= 112) gc -= 112;
            float4v o4;
            o4.x = (f.x - mu) * rstd * g4.x + be4.x;
            o4.y = (f.y - mu) * rstd * g4.y + be4.y;
            o4.z = (f.z - mu) * rstd * g4.z + be4.z;
            o4.w = (f.w - mu) * rstd * g4.w + be4.w;
            *(float4v*)(out + (((size_t)bb * 112 + gr) * 112 + gc) * 256 + l * 4) = o4;
        }
    }
}

extern "C" void kernel_launch(void* const* d_in, const int* in_sizes, int n_in,
                              void* d_out, int out_size, void* d_ws, size_t ws_size,
                              hipStream_t stream) {
    const float* x     = (const float*)d_in[0];
    const float* wq    = (const float*)d_in[1];
    const float* bq    = (const float*)d_in[2];
    const float* wk    = (const float*)d_in[3];
    const float* bk    = (const float*)d_in[4];
    const float* wv    = (const float*)d_in[5];
    const float* bv    = (const float*)d_in[6];
    const float* wo    = (const float*)d_in[7];
    const float* bo    = (const float*)d_in[8];
    const float* gamma = (const float*)d_in[9];
    const float* beta  = (const float*)d_in[10];
    float* out = (float*)d_out;
    unsigned short* wfrag = (unsigned short*)d_ws;   // 4 * 65536 bf16 = 512 KB

    prep_weights<<<1024, 256, 0, stream>>>(wq, wk, wv, wo, wfrag);

    hipFuncSetAttribute((const void*)swin_fused,
                        hipFuncAttributeMaxDynamicSharedMemorySize, LDS_BYTES);
    swin_fused<<<4096, 1024, LDS_BYTES, stream>>>(x, wfrag, bq, bk, bv, bo, gamma, beta, out);
}